// Round 15
// baseline (333.684 us; speedup 1.0000x reference)
//
#include <hip/hip_runtime.h>
#include <hip/hip_fp16.h>
#include <math.h>

#define N 6144
#define H 4
#define CAP 128
#define MINF 1e-15f
#define ONE_EPS  1.0000001192092896f   // fp32(1.0 + 1e-7)
#define ONE_MEPS 0.9999998807907104f   // fp32(1.0 - 1e-7)

__device__ __forceinline__ float wave_reduce_sum(float v) {
    v += __shfl_xor(v, 32, 64);
    v += __shfl_xor(v, 16, 64);
    v += __shfl_xor(v, 8, 64);
    v += __shfl_xor(v, 4, 64);
    v += __shfl_xor(v, 2, 64);
    v += __shfl_xor(v, 1, 64);
    return v;
}

__device__ __forceinline__ float arcosh_f(float z) {
    return logf(z + sqrtf(fmaxf(z * z - 1.0f, 0.0f)));
}

// unpack 8 halfs (loaded as float4) -> 8 floats
__device__ __forceinline__ void h8_to_f(float4 r, float* o) {
    __half2* h = (__half2*)&r;
    #pragma unroll
    for (int q = 0; q < 4; q++) {
        float2 f = __half22float2(h[q]);
        o[2 * q + 0] = f.x;
        o[2 * q + 1] = f.y;
    }
}

// dim permutation absorbed by Bo pack: lane l of lm2 holds dim d(l)
__device__ __forceinline__ int bitrev4(int t) {
    return ((t & 1) << 3) | ((t & 2) << 1) | ((t & 4) >> 1) | ((t & 8) >> 3);
}

// ---------------- K1: prep = logmap0(x) + weight packs + cnt zero ----------------
__global__ void k_prep(const float* __restrict__ x, float* __restrict__ lmv,
                       const float* __restrict__ W_att, const float* __restrict__ W_data,
                       const float* __restrict__ W_out, const float* __restrict__ Wl,
                       float* __restrict__ Bp, float* __restrict__ Bo,
                       float* __restrict__ WlT, int* __restrict__ cnt) {
    int b = blockIdx.x;
    if (b < 1536) {
        int i = b * 4 + (threadIdx.x >> 6);
        int lane = threadIdx.x & 63;
        float y = x[i * 65 + 1 + lane];
        float ss = wave_reduce_sum(y * y);
        float n = fmaxf(sqrtf(ss), MINF);
        float t = fmaxf(x[i * 65], ONE_EPS);
        lmv[i * 64 + lane] = arcosh_f(t) * y / n;
    } else if (b < 1728) {
        int tid = (b - 1536) * 256 + threadIdx.x;
        int m = tid >> 12;
        int r = tid & 4095;
        int k = r >> 6, o = r & 63;
        const float* src;
        if (m < 4) src = W_att + m * 65 * 65;
        else if (m < 8) src = W_data + (m - 4) * 65 * 65;
        else src = W_out + (m - 8) * 65 * 65;
        if (m < 8) {
            Bp[m * 4096 + k * 64 + o] = src[(1 + o) * 65 + (1 + k)];
        } else {
            // k-permuted pack: Bo row k sources original dim d(k)
            int dk = (k & 3) * 16 + bitrev4(k >> 2);
            Bo[(m - 8) * 4096 + k * 64 + o] = src[(1 + o) * 65 + (1 + dk)];
        }
    } else if (b < 1808) {
        // WlT[k*320 + o] = Wl[(1+o)*257 + 1 + k] (o<259), else 0
        int L = ((b - 1728) * 256 + threadIdx.x) * 4;
        int k = L / 320, o0 = L % 320;
        float v[4];
        #pragma unroll
        for (int q = 0; q < 4; q++) {
            int o = o0 + q;
            v[q] = (o < 259) ? Wl[(size_t)(1 + o) * 257 + 1 + k] : 0.f;
        }
        *(float4*)(WlT + L) = make_float4(v[0], v[1], v[2], v[3]);
    } else {
        cnt[(b - 1808) * 256 + threadIdx.x] = 0;
    }
}

// ---------------- K2: PURE adj stream -> compact per-lane find records ---------
// Each block owns a contiguous 36,864 B chunk (2304 uint4), 9 iters, 4 loads in
// flight. NO atomics / NO scatter in this kernel (phase separation diagnostic):
// finds packed as 6-bit codes into a uint2 (5 in lo, 3 in hi, count in hi>>24).
// P(>8 finds/lane) ~ 2e-12 -> immediate-atomic fallback (cnt zeroed in k_prep).
__global__ void __launch_bounds__(256) k_scan1(
        const uint4* __restrict__ a4, uint2* __restrict__ rec,
        int* __restrict__ cnt, int* __restrict__ idx) {
    unsigned sb = blockIdx.x;
    unsigned base4 = sb * 2304u + (unsigned)threadIdx.x;
    unsigned lo = 0, hi = 0;
    int ns = 0;
    uint4 v0 = a4[base4];
    uint4 v1 = a4[base4 + 256u];
    uint4 v2 = a4[base4 + 512u];
    uint4 v3 = a4[base4 + 768u];
    #pragma unroll           // full unroll: static v-rotation (no scratch)
    for (int it = 0; it < 9; it++) {
        uint4 u = (it & 3) == 0 ? v0 : (it & 3) == 1 ? v1
                : (it & 3) == 2 ? v2 : v3;
        if (it + 4 < 9) {
            uint4 nv = a4[base4 + (unsigned)(it + 4) * 256u];
            if ((it & 3) == 0) v0 = nv;
            else if ((it & 3) == 1) v1 = nv;
            else if ((it & 3) == 2) v2 = nv;
            else v3 = nv;
        }
        if (u.x | u.y | u.z | u.w) {
            unsigned uu[4] = {u.x, u.y, u.z, u.w};
            #pragma unroll
            for (int q = 0; q < 4; q++) {
                if (uu[q]) {
                    unsigned code = (unsigned)(it * 4 + q);   // 0..35
                    if (ns < 5) lo |= code << (6 * ns);
                    else if (ns < 8) hi |= code << (6 * (ns - 5));
                    else {
                        // ultra-rare overflow: immediate atomic (cnt ready)
                        unsigned t = (base4 + (unsigned)it * 256u) * 4u + q;
                        int j = t / N;
                        int i = t % N;
                        int pos = atomicAdd(&cnt[i], 1);
                        if (pos < CAP) idx[i * CAP + pos] = j;
                    }
                    ns++;
                }
            }
        }
    }
    hi |= (unsigned)min(ns, 8) << 24;
    rec[sb * 256u + threadIdx.x] = make_uint2(lo, hi);
}

// ---------------- K3: heterogeneous: GEMM1+head-epilogue || CSR scatter --------
// [0,768): GEMM1 tiles (unchanged). [768,4864): replay compact records ->
// atomics+scatter with full TLP, no 151 MB stream competing.
__global__ void __launch_bounds__(256) k_csr_gemm(
        const uint2* __restrict__ rec, int* __restrict__ cnt, int* __restrict__ idx,
        const float* __restrict__ lmv, const float* __restrict__ Bp,
        __half* __restrict__ kv, float2* __restrict__ a0l) {
    __shared__ float smem[64 * 65];
    if (blockIdx.x < 768) {
        float (*As)[64] = (float(*)[64])smem;             // [16][64]
        float (*Bs)[64] = (float(*)[64])(smem + 1024);    // [16][64]
        float (*Cs)[65] = (float(*)[65])smem;             // [64][65]
        int my = blockIdx.x / 96;
        int ix = blockIdx.x % 96;
        const float* Bb = Bp + (size_t)my * 4096;
        int i0 = ix * 64;
        int tid = threadIdx.x;
        int tx = tid & 15, ty = tid >> 4;
        float acc[4][4] = {};
        for (int k0 = 0; k0 < 64; k0 += 16) {
            {
                int mm = tid >> 2, kq = tid & 3;
                float4 v = *(const float4*)(lmv + (size_t)(i0 + mm) * 64 + k0 + kq * 4);
                As[kq * 4 + 0][mm] = v.x;
                As[kq * 4 + 1][mm] = v.y;
                As[kq * 4 + 2][mm] = v.z;
                As[kq * 4 + 3][mm] = v.w;
            }
            {
                int kk = tid >> 4, o4 = tid & 15;
                float4 bvv = *(const float4*)(Bb + (k0 + kk) * 64 + o4 * 4);
                *(float4*)&Bs[kk][o4 * 4] = bvv;
            }
            __syncthreads();
            #pragma unroll
            for (int kk = 0; kk < 16; kk++) {
                float4 av = *(const float4*)&As[kk][ty * 4];
                float4 bv = *(const float4*)&Bs[kk][tx * 4];
                float a[4] = {av.x, av.y, av.z, av.w};
                float b[4] = {bv.x, bv.y, bv.z, bv.w};
                #pragma unroll
                for (int r = 0; r < 4; r++)
                    #pragma unroll
                    for (int c = 0; c < 4; c++) acc[r][c] += a[r] * b[c];
            }
            __syncthreads();
        }
        #pragma unroll
        for (int r = 0; r < 4; r++)
            #pragma unroll
            for (int c = 0; c < 4; c++)
                Cs[ty * 4 + r][tx * 4 + c] = acc[r][c];
        __syncthreads();
        int w = tid >> 6, lane = tid & 63;
        bool isAtt = my < 4;
        int h = my & 3;
        #pragma unroll 1
        for (int r = 0; r < 16; r++) {
            int row = w * 16 + r;
            int i = i0 + row;
            float u = Cs[row][lane];
            float nn = fmaxf(sqrtf(wave_reduce_sum(u * u)), MINF);
            if (isAtt) {
                float sha = sinhf(nn);
                kv[((size_t)h * N + i) * 128 + lane] = __float2half(sha * u / nn);
                if (lane == 0) a0l[h * N + i].x = coshf(nn);
            } else {
                float shd = sinhf(nn), chd = coshf(nn);
                float pvd = (shd * u / nn) / (chd + 1.0f);
                kv[((size_t)h * N + i) * 128 + 64 + lane] = __float2half(pvd);
                float sp = wave_reduce_sum(pvd * pvd);
                if (lane == 0) a0l[h * N + i].y = 2.0f / fmaxf(1.0f - sp, MINF);
            }
        }
    } else {
        unsigned sb = blockIdx.x - 768;
        unsigned r = sb * 256u + (unsigned)threadIdx.x;
        uint2 rc = rec[r];
        int ns = (int)(rc.y >> 24);
        if (ns) {
            unsigned base4 = sb * 2304u + (unsigned)threadIdx.x;
            #pragma unroll
            for (int k = 0; k < 8; k++) {
                if (k < ns) {
                    unsigned code = (k < 5) ? ((rc.x >> (6 * k)) & 63u)
                                            : ((rc.y >> (6 * (k - 5))) & 63u);
                    unsigned it = code >> 2, q = code & 3;
                    unsigned t = (base4 + it * 256u) * 4u + q;
                    int j = t / N;
                    int i = t % N;
                    int pos = atomicAdd(&cnt[i], 1);
                    if (pos < CAP) idx[i * CAP + pos] = j;
                }
            }
        }
    }
}

// ---------------- K4: fused single-pass sparse attention (fp16 kv gathers) -----
__global__ void __launch_bounds__(256) k_attn(
        const int* __restrict__ cnt, const int* __restrict__ idx,
        const __half* __restrict__ kv, const float2* __restrict__ a0l,
        float* __restrict__ lm2) {
    int w = threadIdx.x >> 6, lane = threadIdx.x & 63;
    int gb = blockIdx.x;
    int slot = gb & 7;
    int h = slot >> 1;
    int iblk = (gb >> 3) * 2 + (slot & 1);
    int i = iblk * 4 + w;

    const __half* kvh = kv + (size_t)h * N * 128;
    const float2* a0lh = a0l + (size_t)h * N;
    int c = lane & 3, t = lane >> 2;

    float ai[16];
    {
        float4 r0 = *(const float4*)(kvh + (size_t)i * 128 + c * 16);
        float4 r1 = *(const float4*)(kvh + (size_t)i * 128 + c * 16 + 8);
        h8_to_f(r0, ai);
        h8_to_f(r1, ai + 8);
    }
    float ai0 = a0lh[i].x;
    int nn = min(cnt[i], CAP);

    float accd = 0.f, accss = 0.f;
    float accn16[16] = {};
    for (int base = 0; base < nn; base += 16) {
        int tt = base + t;
        bool act = tt < nn;
        int j = act ? idx[i * CAP + tt] : i;
        float2 al = a0lh[j];
        const __half* row = kvh + (size_t)j * 128;
        float4 b0 = *(const float4*)(row + c * 16);
        float4 b1 = *(const float4*)(row + c * 16 + 8);
        float4 p0 = *(const float4*)(row + 64 + c * 16);
        float4 p1 = *(const float4*)(row + 64 + c * 16 + 8);
        float bv[16], pw[16];
        h8_to_f(b0, bv);
        h8_to_f(b1, bv + 8);
        h8_to_f(p0, pw);
        h8_to_f(p1, pw + 8);
        float d = 0.f;
        #pragma unroll
        for (int k = 0; k < 16; k++) d += ai[k] * bv[k];
        d += __shfl_xor(d, 1, 64);
        d += __shfl_xor(d, 2, 64);
        float theta = fmaxf(ai0 * al.x - d, ONE_EPS);
        float ar = arcosh_f(theta);
        float S = fminf(ar * ar, 50.0f);
        if (!act || j == i) S = 0.f;   // self-edge: theta==1 exactly -> S==0
        float wq = S * al.y;
        if (c == 0) {
            accd += S * (al.y - 1.0f);
            accss += S * S;
        }
        #pragma unroll
        for (int k = 0; k < 16; k++) accn16[k] = fmaf(wq, pw[k], accn16[k]);
    }
    accd = wave_reduce_sum(accd);
    accss = wave_reduce_sum(accss);
    float nrm = fmaxf(sqrtf(accss), 1e-12f);
    float den = fmaxf(accd / nrm, MINF);
    float scl = 1.0f / (nrm * den);

    float r8[8];
    {
        bool b0 = t & 1;
        #pragma unroll
        for (int kk = 0; kk < 8; kk++) {
            float mine = b0 ? accn16[kk + 8] : accn16[kk];
            float send = b0 ? accn16[kk] : accn16[kk + 8];
            r8[kk] = mine + __shfl_xor(send, 4, 64);
        }
    }
    float r4[4];
    {
        bool b1 = t & 2;
        #pragma unroll
        for (int kk = 0; kk < 4; kk++) {
            float mine = b1 ? r8[kk + 4] : r8[kk];
            float send = b1 ? r8[kk] : r8[kk + 4];
            r4[kk] = mine + __shfl_xor(send, 8, 64);
        }
    }
    float r2[2];
    {
        bool b2 = t & 4;
        #pragma unroll
        for (int kk = 0; kk < 2; kk++) {
            float mine = b2 ? r4[kk + 2] : r4[kk];
            float send = b2 ? r4[kk] : r4[kk + 2];
            r2[kk] = mine + __shfl_xor(send, 16, 64);
        }
    }
    float r1;
    {
        bool b3 = t & 8;
        float mine = b3 ? r2[1] : r2[0];
        float send = b3 ? r2[0] : r2[1];
        r1 = mine + __shfl_xor(send, 32, 64);
    }

    float v = -scl * r1;
    float nv = fmaxf(sqrtf(wave_reduce_sum(v * v)), MINF);
    float nc = fminf(nv, ONE_MEPS);
    float mh = tanhf(0.5f * atanhf(nc));
    float md = mh * v / nv;
    float s = wave_reduce_sum(md * md);
    float Dh = fmaxf(1.0f - s, MINF);
    float hb0 = (1.0f + s) / Dh;
    float hbv = 2.0f * md / Dh;
    float nh = fmaxf(2.0f * sqrtf(s) / Dh, MINF);
    float t2 = fmaxf(hb0, ONE_EPS);
    lm2[((size_t)h * N + i) * 64 + lane] = arcosh_f(t2) * hbv / nh;
}

// ---------------- K5 (fused tail, proven R3 layout) ----------------
#define PS 272    // P row stride (floats)
#define BS5 336   // Bs5 row stride
__global__ void __launch_bounds__(256) k_tail(
        const float* __restrict__ lm2, const float* __restrict__ Bo,
        const float* __restrict__ WlT, float* __restrict__ out) {
    __shared__ float smem[5376 + 16 * PS];
    float* As1 = smem;          // [16][68] row-major
    float* Bs1 = smem + 1088;   // [16][64]
    float* Bs5 = smem;          // [16][BS5]
    float* P   = smem + 5376;   // [16][PS]

    int i0 = blockIdx.x * 16;
    int tid = threadIdx.x;
    int ty = tid >> 4;          // row 0..15
    int tx = tid & 15;          // col group

    // ---- GEMM1 + per-head expmap/to_poincare epilogue -> P[r][h*64+o]
    for (int h = 0; h < H; h++) {
        {
            float4 v = *(const float4*)(lm2 + ((size_t)h * N + i0 + ty) * 64 + tx * 4);
            *(float4*)(As1 + ty * 68 + tx * 4) = v;
        }
        float acc[4] = {0.f, 0.f, 0.f, 0.f};
        for (int k0 = 0; k0 < 64; k0 += 16) {
            {
                *(float4*)(Bs1 + ty * 64 + tx * 4) =
                    *(const float4*)(Bo + (size_t)h * 4096 + (k0 + ty) * 64 + tx * 4);
            }
            __syncthreads();
            #pragma unroll
            for (int kk = 0; kk < 16; kk++) {
                float a = As1[ty * 68 + k0 + kk];
                float4 bv = *(const float4*)(Bs1 + kk * 64 + tx * 4);
                acc[0] += a * bv.x;
                acc[1] += a * bv.y;
                acc[2] += a * bv.z;
                acc[3] += a * bv.w;
            }
            __syncthreads();
        }
        float ss = acc[0] * acc[0] + acc[1] * acc[1] + acc[2] * acc[2] + acc[3] * acc[3];
        ss += __shfl_xor(ss, 1, 64);
        ss += __shfl_xor(ss, 2, 64);
        ss += __shfl_xor(ss, 4, 64);
        ss += __shfl_xor(ss, 8, 64);
        float nn = fmaxf(sqrtf(ss), MINF);
        float sh = sinhf(nn), ch = coshf(nn);
        float* Pr = P + ty * PS + h * 64 + tx * 4;
        Pr[0] = (sh * acc[0] / nn) / (ch + 1.0f);
        Pr[1] = (sh * acc[1] / nn) / (ch + 1.0f);
        Pr[2] = (sh * acc[2] / nn) / (ch + 1.0f);
        Pr[3] = (sh * acc[3] / nn) / (ch + 1.0f);
    }
    __syncthreads();

    // ---- to_hyperboloid + logmap0 over the 256-dim row, scale P in place
    {
        float sp = 0.f;
        float4 pl[4];
        #pragma unroll
        for (int q = 0; q < 4; q++) {
            pl[q] = *(const float4*)(P + ty * PS + q * 64 + tx * 4);
            sp += pl[q].x * pl[q].x + pl[q].y * pl[q].y
                + pl[q].z * pl[q].z + pl[q].w * pl[q].w;
        }
        sp += __shfl_xor(sp, 1, 64);
        sp += __shfl_xor(sp, 2, 64);
        sp += __shfl_xor(sp, 4, 64);
        sp += __shfl_xor(sp, 8, 64);
        float Dh = fmaxf(1.0f - sp, MINF);
        float t2 = fmaxf((1.0f + sp) / Dh, ONE_EPS);
        float nh = fmaxf(2.0f * sqrtf(sp) / Dh, MINF);
        float ar2 = arcosh_f(t2);
        #pragma unroll
        for (int q = 0; q < 4; q++) {
            float4 v = pl[q];
            v.x = ar2 * (2.0f * v.x / Dh) / nh;
            v.y = ar2 * (2.0f * v.y / Dh) / nh;
            v.z = ar2 * (2.0f * v.z / Dh) / nh;
            v.w = ar2 * (2.0f * v.w / Dh) / nh;
            *(float4*)(P + ty * PS + q * 64 + tx * 4) = v;
        }
    }
    __syncthreads();

    // ---- GEMM2: C(16x320) = P(16x256) @ WlT(256x320), acc in registers
    float acc2[5][4] = {};
    for (int k0 = 0; k0 < 256; k0 += 16) {
        {
            #pragma unroll
            for (int q = 0; q < 5; q++)
                *(float4*)(Bs5 + ty * BS5 + q * 64 + tx * 4) =
                    *(const float4*)(WlT + (size_t)(k0 + ty) * 320 + q * 64 + tx * 4);
        }
        __syncthreads();
        #pragma unroll
        for (int kq = 0; kq < 4; kq++) {
            float4 pv4 = *(const float4*)(P + ty * PS + k0 + kq * 4);
            float av[4] = {pv4.x, pv4.y, pv4.z, pv4.w};
            #pragma unroll
            for (int j = 0; j < 4; j++) {
                float a = av[j];
                int kk = kq * 4 + j;
                #pragma unroll
                for (int q = 0; q < 5; q++) {
                    float4 bv = *(const float4*)(Bs5 + kk * BS5 + q * 64 + tx * 4);
                    acc2[q][0] += a * bv.x;
                    acc2[q][1] += a * bv.y;
                    acc2[q][2] += a * bv.z;
                    acc2[q][3] += a * bv.w;
                }
            }
        }
        __syncthreads();
    }

    // ---- final expmap0 + hyp_proj epilogue (cols >= 259 are exact zeros)
    float ss2 = 0.f;
    #pragma unroll
    for (int q = 0; q < 5; q++)
        ss2 += acc2[q][0] * acc2[q][0] + acc2[q][1] * acc2[q][1]
             + acc2[q][2] * acc2[q][2] + acc2[q][3] * acc2[q][3];
    ss2 += __shfl_xor(ss2, 1, 64);
    ss2 += __shfl_xor(ss2, 2, 64);
    ss2 += __shfl_xor(ss2, 4, 64);
    ss2 += __shfl_xor(ss2, 8, 64);
    float nv = fmaxf(sqrtf(ss2), MINF);
    float sh2 = sinhf(nv);
    float scale = sh2 / nv;
    size_t ob = (size_t)(i0 + ty) * 260;
    #pragma unroll
    for (int q = 0; q < 4; q++) {
        int o = q * 64 + tx * 4;
        out[ob + 1 + o + 0] = scale * acc2[q][0];
        out[ob + 1 + o + 1] = scale * acc2[q][1];
        out[ob + 1 + o + 2] = scale * acc2[q][2];
        out[ob + 1 + o + 3] = scale * acc2[q][3];
    }
    if (tx == 0) {
        out[ob] = sqrtf(1.0f + sh2 * sh2);
        out[ob + 257] = scale * acc2[4][0];   // col 256
        out[ob + 258] = scale * acc2[4][1];   // col 257
        out[ob + 259] = scale * acc2[4][2];   // col 258
    }
}

extern "C" void kernel_launch(void* const* d_in, const int* in_sizes, int n_in,
                              void* d_out, int out_size, void* d_ws, size_t ws_size,
                              hipStream_t stream) {
    const float* x = (const float*)d_in[0];
    const float* adj = (const float*)d_in[1];
    const float* W_att = (const float*)d_in[2];
    const float* W_data = (const float*)d_in[3];
    const float* W_out = (const float*)d_in[4];
    const float* W_lin = (const float*)d_in[5];
    float* out = (float*)d_out;

    char* ws = (char*)d_ws;
    size_t off = 0;
    auto alloc = [&](size_t bytes) {
        void* ptr = ws + off;
        off += (bytes + 255) & ~(size_t)255;
        return ptr;
    };
    int* cnt = (int*)alloc((size_t)N * 4);
    int* idx = (int*)alloc((size_t)N * CAP * 4);
    uint2* rec = (uint2*)alloc((size_t)4096 * 256 * 8);
    float* lmv = (float*)alloc((size_t)N * 64 * 4);
    __half* kv = (__half*)alloc((size_t)H * N * 128 * 2);
    float2* a0l = (float2*)alloc((size_t)H * N * 8);
    float* lm2 = (float*)alloc((size_t)H * N * 64 * 4);
    float* Bp = (float*)alloc((size_t)8 * 4096 * 4);
    float* Bo = (float*)alloc((size_t)4 * 4096 * 4);
    float* WlT = (float*)alloc((size_t)256 * 320 * 4);

    k_prep<<<1832, 256, 0, stream>>>(x, lmv, W_att, W_data, W_out, W_lin,
                                     Bp, Bo, WlT, cnt);
    k_scan1<<<4096, 256, 0, stream>>>((const uint4*)adj, rec, cnt, idx);
    k_csr_gemm<<<4864, 256, 0, stream>>>(rec, cnt, idx, lmv, Bp, kv, a0l);
    k_attn<<<6144, 256, 0, stream>>>(cnt, idx, kv, a0l, lm2);
    k_tail<<<N / 16, 256, 0, stream>>>(lm2, Bo, WlT, out);
}

// Round 16
// 304.796 us; speedup vs baseline: 1.0948x; 1.0948x over previous
//
#include <hip/hip_runtime.h>
#include <hip/hip_fp16.h>
#include <math.h>

#define N 6144
#define H 4
#define CAP 128
#define MINF 1e-15f
#define ONE_EPS  1.0000001192092896f   // fp32(1.0 + 1e-7)
#define ONE_MEPS 0.9999998807907104f   // fp32(1.0 - 1e-7)

__device__ __forceinline__ float wave_reduce_sum(float v) {
    v += __shfl_xor(v, 32, 64);
    v += __shfl_xor(v, 16, 64);
    v += __shfl_xor(v, 8, 64);
    v += __shfl_xor(v, 4, 64);
    v += __shfl_xor(v, 2, 64);
    v += __shfl_xor(v, 1, 64);
    return v;
}

__device__ __forceinline__ float arcosh_f(float z) {
    return logf(z + sqrtf(fmaxf(z * z - 1.0f, 0.0f)));
}

// unpack 8 halfs (loaded as float4) -> 8 floats
__device__ __forceinline__ void h8_to_f(float4 r, float* o) {
    __half2* h = (__half2*)&r;
    #pragma unroll
    for (int q = 0; q < 4; q++) {
        float2 f = __half22float2(h[q]);
        o[2 * q + 0] = f.x;
        o[2 * q + 1] = f.y;
    }
}

// dim permutation absorbed by Bo pack: lane l of lm2 holds dim d(l)
__device__ __forceinline__ int bitrev4(int t) {
    return ((t & 1) << 3) | ((t & 2) << 1) | ((t & 4) >> 1) | ((t & 8) >> 3);
}

// ---------------- K1: prep = logmap0(x) + weight packs + cnt zero ----------------
__global__ void k_prep(const float* __restrict__ x, float* __restrict__ lmv,
                       const float* __restrict__ W_att, const float* __restrict__ W_data,
                       const float* __restrict__ W_out, const float* __restrict__ Wl,
                       float* __restrict__ Bp, float* __restrict__ Bo,
                       float* __restrict__ WlT, int* __restrict__ cnt) {
    int b = blockIdx.x;
    if (b < 1536) {
        int i = b * 4 + (threadIdx.x >> 6);
        int lane = threadIdx.x & 63;
        float y = x[i * 65 + 1 + lane];
        float ss = wave_reduce_sum(y * y);
        float n = fmaxf(sqrtf(ss), MINF);
        float t = fmaxf(x[i * 65], ONE_EPS);
        lmv[i * 64 + lane] = arcosh_f(t) * y / n;
    } else if (b < 1728) {
        int tid = (b - 1536) * 256 + threadIdx.x;
        int m = tid >> 12;
        int r = tid & 4095;
        int k = r >> 6, o = r & 63;
        const float* src;
        if (m < 4) src = W_att + m * 65 * 65;
        else if (m < 8) src = W_data + (m - 4) * 65 * 65;
        else src = W_out + (m - 8) * 65 * 65;
        if (m < 8) {
            Bp[m * 4096 + k * 64 + o] = src[(1 + o) * 65 + (1 + k)];
        } else {
            // k-permuted pack: Bo row k sources original dim d(k)
            int dk = (k & 3) * 16 + bitrev4(k >> 2);
            Bo[(m - 8) * 4096 + k * 64 + o] = src[(1 + o) * 65 + (1 + dk)];
        }
    } else if (b < 1808) {
        // WlT[k*320 + o] = Wl[(1+o)*257 + 1 + k] (o<259), else 0
        int L = ((b - 1728) * 256 + threadIdx.x) * 4;
        int k = L / 320, o0 = L % 320;
        float v[4];
        #pragma unroll
        for (int q = 0; q < 4; q++) {
            int o = o0 + q;
            v[q] = (o < 259) ? Wl[(size_t)(1 + o) * 257 + 1 + k] : 0.f;
        }
        *(float4*)(WlT + L) = make_float4(v[0], v[1], v[2], v[3]);
    } else {
        cnt[(b - 1808) * 256 + threadIdx.x] = 0;
    }
}

// ---------------- K2: heterogeneous: GEMM1+head-epilogue || CSR build ----------
// Scan: LINEAR per-block layout (best measured). Each scan block owns a
// CONTIGUOUS 36,864 B chunk of adj (2304 uint4), iterated wave-contiguously
// (step 256 uint4), 4 loads in flight, deferred atomics (R11). Falsified
// alternatives: strided layout, 2-deep pipe, float-gate, in-loop atomics,
// XCD-private segments, phase-separated scatter (R15: +28 us).
__global__ void __launch_bounds__(256) k_csr_gemm(
        const float* __restrict__ adj, int* __restrict__ cnt, int* __restrict__ idx,
        const float* __restrict__ lmv, const float* __restrict__ Bp,
        __half* __restrict__ kv, float2* __restrict__ a0l) {
    __shared__ float smem[64 * 65];
    if (blockIdx.x < 768) {
        float (*As)[64] = (float(*)[64])smem;             // [16][64]
        float (*Bs)[64] = (float(*)[64])(smem + 1024);    // [16][64]
        float (*Cs)[65] = (float(*)[65])smem;             // [64][65]
        int my = blockIdx.x / 96;
        int ix = blockIdx.x % 96;
        const float* Bb = Bp + (size_t)my * 4096;
        int i0 = ix * 64;
        int tid = threadIdx.x;
        int tx = tid & 15, ty = tid >> 4;
        float acc[4][4] = {};
        for (int k0 = 0; k0 < 64; k0 += 16) {
            {
                int mm = tid >> 2, kq = tid & 3;
                float4 v = *(const float4*)(lmv + (size_t)(i0 + mm) * 64 + k0 + kq * 4);
                As[kq * 4 + 0][mm] = v.x;
                As[kq * 4 + 1][mm] = v.y;
                As[kq * 4 + 2][mm] = v.z;
                As[kq * 4 + 3][mm] = v.w;
            }
            {
                int kk = tid >> 4, o4 = tid & 15;
                float4 bvv = *(const float4*)(Bb + (k0 + kk) * 64 + o4 * 4);
                *(float4*)&Bs[kk][o4 * 4] = bvv;
            }
            __syncthreads();
            #pragma unroll
            for (int kk = 0; kk < 16; kk++) {
                float4 av = *(const float4*)&As[kk][ty * 4];
                float4 bv = *(const float4*)&Bs[kk][tx * 4];
                float a[4] = {av.x, av.y, av.z, av.w};
                float b[4] = {bv.x, bv.y, bv.z, bv.w};
                #pragma unroll
                for (int r = 0; r < 4; r++)
                    #pragma unroll
                    for (int c = 0; c < 4; c++) acc[r][c] += a[r] * b[c];
            }
            __syncthreads();
        }
        #pragma unroll
        for (int r = 0; r < 4; r++)
            #pragma unroll
            for (int c = 0; c < 4; c++)
                Cs[ty * 4 + r][tx * 4 + c] = acc[r][c];
        __syncthreads();
        int w = tid >> 6, lane = tid & 63;
        bool isAtt = my < 4;
        int h = my & 3;
        #pragma unroll 1
        for (int r = 0; r < 16; r++) {
            int row = w * 16 + r;
            int i = i0 + row;
            float u = Cs[row][lane];
            float nn = fmaxf(sqrtf(wave_reduce_sum(u * u)), MINF);
            if (isAtt) {
                float sha = sinhf(nn);
                kv[((size_t)h * N + i) * 128 + lane] = __float2half(sha * u / nn);
                if (lane == 0) a0l[h * N + i].x = coshf(nn);
            } else {
                float shd = sinhf(nn), chd = coshf(nn);
                float pvd = (shd * u / nn) / (chd + 1.0f);
                kv[((size_t)h * N + i) * 128 + 64 + lane] = __float2half(pvd);
                float sp = wave_reduce_sum(pvd * pvd);
                if (lane == 0) a0l[h * N + i].y = 2.0f / fmaxf(1.0f - sp, MINF);
            }
        }
    } else {
        // adj scan: contiguous 2304-uint4 chunk per block, 9 iters, 4 in flight,
        // deferred atomics. adj entries {0.0f,1.0f} -> (bits!=0) <=> (>0.01f).
        const uint4* a4 = (const uint4*)adj;
        unsigned sb = blockIdx.x - 768;
        unsigned base4 = sb * 2304u + (unsigned)threadIdx.x;
        unsigned s0 = 0, s1 = 0, s2 = 0, s3 = 0;
        int ns = 0;
        uint4 v0 = a4[base4];
        uint4 v1 = a4[base4 + 256u];
        uint4 v2 = a4[base4 + 512u];
        uint4 v3 = a4[base4 + 768u];
        #pragma unroll           // full unroll: static v-rotation (no scratch)
        for (int it = 0; it < 9; it++) {
            uint4 u = (it & 3) == 0 ? v0 : (it & 3) == 1 ? v1
                    : (it & 3) == 2 ? v2 : v3;
            if (it + 4 < 9) {
                uint4 nv = a4[base4 + (unsigned)(it + 4) * 256u];
                if ((it & 3) == 0) v0 = nv;
                else if ((it & 3) == 1) v1 = nv;
                else if ((it & 3) == 2) v2 = nv;
                else v3 = nv;
            }
            if (u.x | u.y | u.z | u.w) {
                unsigned uu[4] = {u.x, u.y, u.z, u.w};
                #pragma unroll
                for (int q = 0; q < 4; q++) {
                    if (uu[q]) {
                        unsigned code = (unsigned)(it * 4 + q);   // 0..35
                        if (ns == 0) s0 = code;
                        else if (ns == 1) s1 = code;
                        else if (ns == 2) s2 = code;
                        else if (ns == 3) s3 = code;
                        else {
                            // overflow (>4 finds/lane): P ~ 1e-5, immediate path
                            unsigned t = (base4 + (unsigned)it * 256u) * 4u + q;
                            int j = t / N;
                            int i = t % N;
                            int pos = atomicAdd(&cnt[i], 1);
                            if (pos < CAP) idx[i * CAP + pos] = j;
                        }
                        ns++;
                    }
                }
            }
        }
        // drain: all atomics issued post-loop (no loads left to block)
        #pragma unroll
        for (int k = 0; k < 4; k++) {
            if (ns > k) {
                unsigned code = (k == 0) ? s0 : (k == 1) ? s1 : (k == 2) ? s2 : s3;
                unsigned it = code >> 2, q = code & 3;
                unsigned t = (base4 + it * 256u) * 4u + q;
                int j = t / N;
                int i = t % N;
                int pos = atomicAdd(&cnt[i], 1);
                if (pos < CAP) idx[i * CAP + pos] = j;
            }
        }
    }
}

// ---------------- K3: fused single-pass sparse attention (fp16 kv gathers) -----
__global__ void __launch_bounds__(256) k_attn(
        const int* __restrict__ cnt, const int* __restrict__ idx,
        const __half* __restrict__ kv, const float2* __restrict__ a0l,
        float* __restrict__ lm2) {
    int w = threadIdx.x >> 6, lane = threadIdx.x & 63;
    int gb = blockIdx.x;
    int slot = gb & 7;
    int h = slot >> 1;
    int iblk = (gb >> 3) * 2 + (slot & 1);
    int i = iblk * 4 + w;

    const __half* kvh = kv + (size_t)h * N * 128;
    const float2* a0lh = a0l + (size_t)h * N;
    int c = lane & 3, t = lane >> 2;

    float ai[16];
    {
        float4 r0 = *(const float4*)(kvh + (size_t)i * 128 + c * 16);
        float4 r1 = *(const float4*)(kvh + (size_t)i * 128 + c * 16 + 8);
        h8_to_f(r0, ai);
        h8_to_f(r1, ai + 8);
    }
    float ai0 = a0lh[i].x;
    int nn = min(cnt[i], CAP);

    float accd = 0.f, accss = 0.f;
    float accn16[16] = {};
    for (int base = 0; base < nn; base += 16) {
        int tt = base + t;
        bool act = tt < nn;
        int j = act ? idx[i * CAP + tt] : i;
        float2 al = a0lh[j];
        const __half* row = kvh + (size_t)j * 128;
        float4 b0 = *(const float4*)(row + c * 16);
        float4 b1 = *(const float4*)(row + c * 16 + 8);
        float4 p0 = *(const float4*)(row + 64 + c * 16);
        float4 p1 = *(const float4*)(row + 64 + c * 16 + 8);
        float bv[16], pw[16];
        h8_to_f(b0, bv);
        h8_to_f(b1, bv + 8);
        h8_to_f(p0, pw);
        h8_to_f(p1, pw + 8);
        float d = 0.f;
        #pragma unroll
        for (int k = 0; k < 16; k++) d += ai[k] * bv[k];
        d += __shfl_xor(d, 1, 64);
        d += __shfl_xor(d, 2, 64);
        float theta = fmaxf(ai0 * al.x - d, ONE_EPS);
        float ar = arcosh_f(theta);
        float S = fminf(ar * ar, 50.0f);
        if (!act || j == i) S = 0.f;   // self-edge: theta==1 exactly -> S==0
        float wq = S * al.y;
        if (c == 0) {
            accd += S * (al.y - 1.0f);
            accss += S * S;
        }
        #pragma unroll
        for (int k = 0; k < 16; k++) accn16[k] = fmaf(wq, pw[k], accn16[k]);
    }
    accd = wave_reduce_sum(accd);
    accss = wave_reduce_sum(accss);
    float nrm = fmaxf(sqrtf(accss), 1e-12f);
    float den = fmaxf(accd / nrm, MINF);
    float scl = 1.0f / (nrm * den);

    float r8[8];
    {
        bool b0 = t & 1;
        #pragma unroll
        for (int kk = 0; kk < 8; kk++) {
            float mine = b0 ? accn16[kk + 8] : accn16[kk];
            float send = b0 ? accn16[kk] : accn16[kk + 8];
            r8[kk] = mine + __shfl_xor(send, 4, 64);
        }
    }
    float r4[4];
    {
        bool b1 = t & 2;
        #pragma unroll
        for (int kk = 0; kk < 4; kk++) {
            float mine = b1 ? r8[kk + 4] : r8[kk];
            float send = b1 ? r8[kk] : r8[kk + 4];
            r4[kk] = mine + __shfl_xor(send, 8, 64);
        }
    }
    float r2[2];
    {
        bool b2 = t & 4;
        #pragma unroll
        for (int kk = 0; kk < 2; kk++) {
            float mine = b2 ? r4[kk + 2] : r4[kk];
            float send = b2 ? r4[kk] : r4[kk + 2];
            r2[kk] = mine + __shfl_xor(send, 16, 64);
        }
    }
    float r1;
    {
        bool b3 = t & 8;
        float mine = b3 ? r2[1] : r2[0];
        float send = b3 ? r2[0] : r2[1];
        r1 = mine + __shfl_xor(send, 32, 64);
    }

    float v = -scl * r1;
    float nv = fmaxf(sqrtf(wave_reduce_sum(v * v)), MINF);
    float nc = fminf(nv, ONE_MEPS);
    float mh = tanhf(0.5f * atanhf(nc));
    float md = mh * v / nv;
    float s = wave_reduce_sum(md * md);
    float Dh = fmaxf(1.0f - s, MINF);
    float hb0 = (1.0f + s) / Dh;
    float hbv = 2.0f * md / Dh;
    float nh = fmaxf(2.0f * sqrtf(s) / Dh, MINF);
    float t2 = fmaxf(hb0, ONE_EPS);
    lm2[((size_t)h * N + i) * 64 + lane] = arcosh_f(t2) * hbv / nh;
}

// ---------------- K4 (fused tail, proven R3 layout) ----------------
#define PS 272    // P row stride (floats)
#define BS5 336   // Bs5 row stride
__global__ void __launch_bounds__(256) k_tail(
        const float* __restrict__ lm2, const float* __restrict__ Bo,
        const float* __restrict__ WlT, float* __restrict__ out) {
    __shared__ float smem[5376 + 16 * PS];
    float* As1 = smem;          // [16][68] row-major
    float* Bs1 = smem + 1088;   // [16][64]
    float* Bs5 = smem;          // [16][BS5]
    float* P   = smem + 5376;   // [16][PS]

    int i0 = blockIdx.x * 16;
    int tid = threadIdx.x;
    int ty = tid >> 4;          // row 0..15
    int tx = tid & 15;          // col group

    // ---- GEMM1 + per-head expmap/to_poincare epilogue -> P[r][h*64+o]
    for (int h = 0; h < H; h++) {
        {
            float4 v = *(const float4*)(lm2 + ((size_t)h * N + i0 + ty) * 64 + tx * 4);
            *(float4*)(As1 + ty * 68 + tx * 4) = v;
        }
        float acc[4] = {0.f, 0.f, 0.f, 0.f};
        for (int k0 = 0; k0 < 64; k0 += 16) {
            {
                *(float4*)(Bs1 + ty * 64 + tx * 4) =
                    *(const float4*)(Bo + (size_t)h * 4096 + (k0 + ty) * 64 + tx * 4);
            }
            __syncthreads();
            #pragma unroll
            for (int kk = 0; kk < 16; kk++) {
                float a = As1[ty * 68 + k0 + kk];
                float4 bv = *(const float4*)(Bs1 + kk * 64 + tx * 4);
                acc[0] += a * bv.x;
                acc[1] += a * bv.y;
                acc[2] += a * bv.z;
                acc[3] += a * bv.w;
            }
            __syncthreads();
        }
        float ss = acc[0] * acc[0] + acc[1] * acc[1] + acc[2] * acc[2] + acc[3] * acc[3];
        ss += __shfl_xor(ss, 1, 64);
        ss += __shfl_xor(ss, 2, 64);
        ss += __shfl_xor(ss, 4, 64);
        ss += __shfl_xor(ss, 8, 64);
        float nn = fmaxf(sqrtf(ss), MINF);
        float sh = sinhf(nn), ch = coshf(nn);
        float* Pr = P + ty * PS + h * 64 + tx * 4;
        Pr[0] = (sh * acc[0] / nn) / (ch + 1.0f);
        Pr[1] = (sh * acc[1] / nn) / (ch + 1.0f);
        Pr[2] = (sh * acc[2] / nn) / (ch + 1.0f);
        Pr[3] = (sh * acc[3] / nn) / (ch + 1.0f);
    }
    __syncthreads();

    // ---- to_hyperboloid + logmap0 over the 256-dim row, scale P in place
    {
        float sp = 0.f;
        float4 pl[4];
        #pragma unroll
        for (int q = 0; q < 4; q++) {
            pl[q] = *(const float4*)(P + ty * PS + q * 64 + tx * 4);
            sp += pl[q].x * pl[q].x + pl[q].y * pl[q].y
                + pl[q].z * pl[q].z + pl[q].w * pl[q].w;
        }
        sp += __shfl_xor(sp, 1, 64);
        sp += __shfl_xor(sp, 2, 64);
        sp += __shfl_xor(sp, 4, 64);
        sp += __shfl_xor(sp, 8, 64);
        float Dh = fmaxf(1.0f - sp, MINF);
        float t2 = fmaxf((1.0f + sp) / Dh, ONE_EPS);
        float nh = fmaxf(2.0f * sqrtf(sp) / Dh, MINF);
        float ar2 = arcosh_f(t2);
        #pragma unroll
        for (int q = 0; q < 4; q++) {
            float4 v = pl[q];
            v.x = ar2 * (2.0f * v.x / Dh) / nh;
            v.y = ar2 * (2.0f * v.y / Dh) / nh;
            v.z = ar2 * (2.0f * v.z / Dh) / nh;
            v.w = ar2 * (2.0f * v.w / Dh) / nh;
            *(float4*)(P + ty * PS + q * 64 + tx * 4) = v;
        }
    }
    __syncthreads();

    // ---- GEMM2: C(16x320) = P(16x256) @ WlT(256x320), acc in registers
    float acc2[5][4] = {};
    for (int k0 = 0; k0 < 256; k0 += 16) {
        {
            #pragma unroll
            for (int q = 0; q < 5; q++)
                *(float4*)(Bs5 + ty * BS5 + q * 64 + tx * 4) =
                    *(const float4*)(WlT + (size_t)(k0 + ty) * 320 + q * 64 + tx * 4);
        }
        __syncthreads();
        #pragma unroll
        for (int kq = 0; kq < 4; kq++) {
            float4 pv4 = *(const float4*)(P + ty * PS + k0 + kq * 4);
            float av[4] = {pv4.x, pv4.y, pv4.z, pv4.w};
            #pragma unroll
            for (int j = 0; j < 4; j++) {
                float a = av[j];
                int kk = kq * 4 + j;
                #pragma unroll
                for (int q = 0; q < 5; q++) {
                    float4 bv = *(const float4*)(Bs5 + kk * BS5 + q * 64 + tx * 4);
                    acc2[q][0] += a * bv.x;
                    acc2[q][1] += a * bv.y;
                    acc2[q][2] += a * bv.z;
                    acc2[q][3] += a * bv.w;
                }
            }
        }
        __syncthreads();
    }

    // ---- final expmap0 + hyp_proj epilogue (cols >= 259 are exact zeros)
    float ss2 = 0.f;
    #pragma unroll
    for (int q = 0; q < 5; q++)
        ss2 += acc2[q][0] * acc2[q][0] + acc2[q][1] * acc2[q][1]
             + acc2[q][2] * acc2[q][2] + acc2[q][3] * acc2[q][3];
    ss2 += __shfl_xor(ss2, 1, 64);
    ss2 += __shfl_xor(ss2, 2, 64);
    ss2 += __shfl_xor(ss2, 4, 64);
    ss2 += __shfl_xor(ss2, 8, 64);
    float nv = fmaxf(sqrtf(ss2), MINF);
    float sh2 = sinhf(nv);
    float scale = sh2 / nv;
    size_t ob = (size_t)(i0 + ty) * 260;
    #pragma unroll
    for (int q = 0; q < 4; q++) {
        int o = q * 64 + tx * 4;
        out[ob + 1 + o + 0] = scale * acc2[q][0];
        out[ob + 1 + o + 1] = scale * acc2[q][1];
        out[ob + 1 + o + 2] = scale * acc2[q][2];
        out[ob + 1 + o + 3] = scale * acc2[q][3];
    }
    if (tx == 0) {
        out[ob] = sqrtf(1.0f + sh2 * sh2);
        out[ob + 257] = scale * acc2[4][0];   // col 256
        out[ob + 258] = scale * acc2[4][1];   // col 257
        out[ob + 259] = scale * acc2[4][2];   // col 258
    }
}

extern "C" void kernel_launch(void* const* d_in, const int* in_sizes, int n_in,
                              void* d_out, int out_size, void* d_ws, size_t ws_size,
                              hipStream_t stream) {
    const float* x = (const float*)d_in[0];
    const float* adj = (const float*)d_in[1];
    const float* W_att = (const float*)d_in[2];
    const float* W_data = (const float*)d_in[3];
    const float* W_out = (const float*)d_in[4];
    const float* W_lin = (const float*)d_in[5];
    float* out = (float*)d_out;

    char* ws = (char*)d_ws;
    size_t off = 0;
    auto alloc = [&](size_t bytes) {
        void* ptr = ws + off;
        off += (bytes + 255) & ~(size_t)255;
        return ptr;
    };
    int* cnt = (int*)alloc((size_t)N * 4);
    int* idx = (int*)alloc((size_t)N * CAP * 4);
    float* lmv = (float*)alloc((size_t)N * 64 * 4);
    __half* kv = (__half*)alloc((size_t)H * N * 128 * 2);
    float2* a0l = (float2*)alloc((size_t)H * N * 8);
    float* lm2 = (float*)alloc((size_t)H * N * 64 * 4);
    float* Bp = (float*)alloc((size_t)8 * 4096 * 4);
    float* Bo = (float*)alloc((size_t)4 * 4096 * 4);
    float* WlT = (float*)alloc((size_t)256 * 320 * 4);

    k_prep<<<1832, 256, 0, stream>>>(x, lmv, W_att, W_data, W_out, W_lin,
                                     Bp, Bo, WlT, cnt);
    k_csr_gemm<<<4864, 256, 0, stream>>>(adj, cnt, idx, lmv, Bp, kv, a0l);
    k_attn<<<6144, 256, 0, stream>>>(cnt, idx, kv, a0l, lm2);
    k_tail<<<N / 16, 256, 0, stream>>>(lm2, Bo, WlT, out);
}